// Round 8
// baseline (571.805 us; speedup 1.0000x reference)
//
#include <hip/hip_runtime.h>

#define NN 50000
#define NE 800000
#define CC 128
#define SLAB (NN * CC)
#define BN_EPS 1e-5f

typedef __attribute__((ext_vector_type(8))) short bf16x8;
typedef __attribute__((ext_vector_type(4))) float f32x4;
typedef unsigned short ushort_t;
typedef unsigned int uint_t;

__device__ inline ushort_t f2bf(float v) {
  unsigned u = __builtin_bit_cast(unsigned, v);
  unsigned r = u + 0x7FFFu + ((u >> 16) & 1u);
  return (ushort_t)(r >> 16);
}
__device__ inline float bf2f(unsigned lo16) { return __builtin_bit_cast(float, lo16 << 16); }

// ---------------- utility ----------------
__global__ void zero_int_kernel(int* __restrict__ p, int n) {
  int i = blockIdx.x * blockDim.x + threadIdx.x;
  if (i < n) p[i] = 0;
}

// ---------------- CSR build ----------------
__global__ void count_kernel(const int* __restrict__ dst, int* __restrict__ counts) {
  int e = blockIdx.x * blockDim.x + threadIdx.x;
  if (e < NE) atomicAdd(&counts[dst[e]], 1);
}

__global__ void scan1_kernel(const int* __restrict__ counts, int* __restrict__ excl,
                             int* __restrict__ blocksum) {
  __shared__ int s[256];
  int t = threadIdx.x;
  int i = blockIdx.x * 256 + t;
  int v = (i < NN) ? counts[i] : 0;
  s[t] = v;
  for (int off = 1; off < 256; off <<= 1) {
    __syncthreads();
    int add = (t >= off) ? s[t - off] : 0;
    __syncthreads();
    s[t] += add;
  }
  __syncthreads();
  if (i < NN) excl[i] = s[t] - v;
  if (t == 255) blocksum[blockIdx.x] = s[255];
}

__global__ void scan2_kernel(int* __restrict__ blocksum, int nb) {
  __shared__ int s[256];
  int t = threadIdx.x;
  int v = (t < nb) ? blocksum[t] : 0;
  s[t] = v;
  for (int off = 1; off < 256; off <<= 1) {
    __syncthreads();
    int add = (t >= off) ? s[t - off] : 0;
    __syncthreads();
    s[t] += add;
  }
  __syncthreads();
  if (t < nb) blocksum[t] = s[t] - v;
}

__global__ void scan3_kernel(int* __restrict__ excl, const int* __restrict__ blocksum) {
  int i = blockIdx.x * 256 + threadIdx.x;
  if (i < NN) excl[i] += blocksum[blockIdx.x];
}

__global__ void fill_kernel(const int* __restrict__ src, const int* __restrict__ dst,
                            const int* __restrict__ starts, int* __restrict__ fill,
                            int* __restrict__ bucket) {
  int e = blockIdx.x * blockDim.x + threadIdx.x;
  if (e < NE) {
    int d = dst[e];
    int pos = atomicAdd(&fill[d], 1);
    bucket[starts[d] + pos] = src[e];
  }
}

// ---------------- W prep: split + pack into per-(ks,nt) 64-lane fragments ----------------
__global__ void prep_w_kernel(const float* __restrict__ fh_W, const float* __restrict__ W1,
                              const float* __restrict__ W2, short* __restrict__ whi,
                              short* __restrict__ wlo) {
  int m = blockIdx.x;
  const float* src = (m == 0) ? fh_W : ((m <= 3) ? W1 + (m - 1) * CC * CC : W2 + (m - 4) * CC * CC);
  short* hi = whi + m * CC * CC;
  short* lo = wlo + m * CC * CC;
  for (int it = 0; it < 64; ++it) {
    int idx = it * 256 + threadIdx.x;  // 0..16383
    int j = idx & 7;
    int l = (idx >> 3) & 63;
    int nt = (idx >> 9) & 7;
    int ks = idx >> 12;
    int n = nt * 16 + (l & 15);
    int k = ks * 32 + ((l >> 4) << 3) + j;
    float v = src[k * CC + n];
    unsigned u = __builtin_bit_cast(unsigned, v);
    unsigned short h = (unsigned short)(u >> 16);
    float hf = __builtin_bit_cast(float, ((unsigned)h) << 16);
    float r = v - hf;
    unsigned ur = __builtin_bit_cast(unsigned, r);
    hi[idx] = (short)h;
    lo[idx] = (short)(ur >> 16);
  }
}

// ---------------- GEMM0 (no LDS): out = x @ fh_W + b; writes fp32 slab + slice-major h16s ----------------
__global__ __launch_bounds__(256) void gemm0_kernel(
    const float* __restrict__ A, const short* __restrict__ Wp_hi, const short* __restrict__ Wp_lo,
    const float* __restrict__ bias, float* __restrict__ out, ushort_t* __restrict__ h16s) {
  const int t = threadIdx.x;
  const int l = t & 63;
  const int wv = t >> 6;
  const int m0 = blockIdx.x * 64 + wv * 16;
  const int row = m0 + (l & 15);
  const int kg = (l >> 4) * 8;

  f32x4 acc[8];
#pragma unroll
  for (int i = 0; i < 8; ++i) acc[i] = (f32x4){0.f, 0.f, 0.f, 0.f};

#pragma unroll
  for (int ks = 0; ks < 4; ++ks) {
    float av[8];
    if (row < NN) {
      const float* ap = &A[row * CC + ks * 32 + kg];
      float4 v0 = *(const float4*)ap;
      float4 v1 = *(const float4*)(ap + 4);
      av[0] = v0.x; av[1] = v0.y; av[2] = v0.z; av[3] = v0.w;
      av[4] = v1.x; av[5] = v1.y; av[6] = v1.z; av[7] = v1.w;
    } else {
#pragma unroll
      for (int i = 0; i < 8; ++i) av[i] = 0.f;
    }
    bf16x8 ah, al;
#pragma unroll
    for (int i = 0; i < 8; ++i) {
      unsigned u = __builtin_bit_cast(unsigned, av[i]);
      unsigned short hbits = (unsigned short)(u >> 16);
      float hf = __builtin_bit_cast(float, ((unsigned)hbits) << 16);
      float r = av[i] - hf;
      unsigned ur = __builtin_bit_cast(unsigned, r);
      ah[i] = (short)hbits;
      al[i] = (short)(ur >> 16);
    }
#pragma unroll
    for (int nt = 0; nt < 8; ++nt) {
      const int base = (ks * 8 + nt) * 512 + l * 8;
      bf16x8 wh = *(const bf16x8*)&Wp_hi[base];
      bf16x8 wl = *(const bf16x8*)&Wp_lo[base];
      acc[nt] = __builtin_amdgcn_mfma_f32_16x16x32_bf16(ah, wh, acc[nt], 0, 0, 0);
      acc[nt] = __builtin_amdgcn_mfma_f32_16x16x32_bf16(al, wh, acc[nt], 0, 0, 0);
      acc[nt] = __builtin_amdgcn_mfma_f32_16x16x32_bf16(ah, wl, acc[nt], 0, 0, 0);
    }
  }

  const int rbase = m0 + (l >> 4) * 4;
  const int cn = l & 15;
#pragma unroll
  for (int nt = 0; nt < 8; ++nt) {
    int c = nt * 16 + cn;
    float bv = bias[c];
#pragma unroll
    for (int r = 0; r < 4; ++r) {
      int rr = rbase + r;
      if (rr < NN) {
        float v = acc[nt][r] + bv;
        out[rr * CC + c] = v;
        h16s[(nt * NN + rr) * 16 + cn] = f2bf(v);  // slice nt, offset cn
      }
    }
  }
}

// ---------------- channel-sliced gather: aggs[s] = bf16(h + sum_nb h), slice s = blockIdx&7 ----------------
// One 16-lane group per node; group's lanes: j8 = uint slot (2ch), half = neighbor parity.
// Slice table = 1.6 MB -> L2-resident per XCD (blockIdx%8 round-robin).
__global__ __launch_bounds__(256) void gather_kernel(
    const ushort_t* __restrict__ h16s, const int* __restrict__ starts,
    const int* __restrict__ counts, const int* __restrict__ bucket,
    ushort_t* __restrict__ aggs) {
  const int slice = blockIdx.x & 7;
  const int t = threadIdx.x;
  const int g16 = t >> 4;
  const int lane16 = t & 15;
  const int j8 = lane16 & 7;
  const int half = lane16 >> 3;
  const int node = (blockIdx.x >> 3) * 16 + g16;   // 25000 blocks -> exactly covers 50000
  const int wl_base = t & 48;                       // group base lane within wave
  const uint_t* tbl = (const uint_t*)h16s + slice * (NN * 8);

  float a0 = 0.f, a1 = 0.f;
  if (half == 0) {
    uint_t u = tbl[node * 8 + j8];
    a0 = bf2f(u & 0xFFFFu);
    a1 = bf2f(u >> 16);
  }
  const int s = starts[node];
  const int n = counts[node];
  for (int base = 0; base < n; base += 16) {
    int nb = n - base;
    if (nb > 16) nb = 16;
    int idx = (lane16 < nb) ? bucket[s + base + lane16] : -1;
#pragma unroll
    for (int k = 0; k < 8; ++k) {
      int sr = __shfl(idx, wl_base + 2 * k + half);
      if (sr >= 0) {
        uint_t u = tbl[sr * 8 + j8];
        a0 += bf2f(u & 0xFFFFu);
        a1 += bf2f(u >> 16);
      }
    }
  }
  a0 += __shfl_xor(a0, 8);
  a1 += __shfl_xor(a1, 8);
  if (half == 0) {
    ((uint_t*)aggs)[slice * (NN * 8) + node * 8 + j8] =
        (uint_t)f2bf(a0) | ((uint_t)f2bf(a1) << 16);
  }
}

// ---------------- GEMM1: tmp16 = bf16(aggs @ W1 + b1), stats1 (A slice-major bf16) ----------------
__global__ __launch_bounds__(256) void gemm1_kernel(
    const ushort_t* __restrict__ aggs, const short* __restrict__ Wp_hi,
    const short* __restrict__ Wp_lo, const float* __restrict__ bias,
    ushort_t* __restrict__ tmp16, float* __restrict__ stats_out) {
  __shared__ float sred[2 * CC];
  const int t = threadIdx.x;
  const int l = t & 63;
  const int wv = t >> 6;
  const int m0 = blockIdx.x * 64 + wv * 16;
  const int row = m0 + (l & 15);
  const int kg = (l >> 4) * 8;
  sred[t] = 0.f;

  f32x4 acc[8];
#pragma unroll
  for (int i = 0; i < 8; ++i) acc[i] = (f32x4){0.f, 0.f, 0.f, 0.f};

#pragma unroll
  for (int ks = 0; ks < 4; ++ks) {
    const int ch0 = ks * 32 + kg;
    bf16x8 ah;
    if (row < NN) {
      ah = *(const bf16x8*)&aggs[((ch0 >> 4) * NN + row) * 16 + (ch0 & 15)];
    } else {
#pragma unroll
      for (int i = 0; i < 8; ++i) ah[i] = 0;
    }
#pragma unroll
    for (int nt = 0; nt < 8; ++nt) {
      const int base = (ks * 8 + nt) * 512 + l * 8;
      bf16x8 wh = *(const bf16x8*)&Wp_hi[base];
      bf16x8 wl = *(const bf16x8*)&Wp_lo[base];
      acc[nt] = __builtin_amdgcn_mfma_f32_16x16x32_bf16(ah, wh, acc[nt], 0, 0, 0);
      acc[nt] = __builtin_amdgcn_mfma_f32_16x16x32_bf16(ah, wl, acc[nt], 0, 0, 0);
    }
  }

  __syncthreads();
  const int rbase = m0 + (l >> 4) * 4;
  const int cn = l & 15;
#pragma unroll
  for (int nt = 0; nt < 8; ++nt) {
    int c = nt * 16 + cn;
    float bv = bias[c];
    float s = 0.f, qq = 0.f;
#pragma unroll
    for (int r = 0; r < 4; ++r) {
      int rr = rbase + r;
      if (rr < NN) {
        float v = acc[nt][r] + bv;
        tmp16[rr * CC + c] = f2bf(v);
        s += v; qq += v * v;
      }
    }
    s += __shfl_xor(s, 16); s += __shfl_xor(s, 32);
    qq += __shfl_xor(qq, 16); qq += __shfl_xor(qq, 32);
    if ((l >> 4) == 0) {
      atomicAdd(&sred[c], s);
      atomicAdd(&sred[CC + c], qq);
    }
  }
  __syncthreads();
  atomicAdd(&stats_out[t], sred[t]);
}

// ---------------- GEMM2: tmp16 = bf16(relu(BN1(tmp16)) @ W2 + b2) in-place, stats2 ----------------
// In-place safe: each wave reads only its own 16 rows (ch-major) before writing them.
__global__ __launch_bounds__(256) void gemm2_kernel(
    ushort_t* __restrict__ tmp16, const short* __restrict__ Wp_hi,
    const short* __restrict__ Wp_lo, const float* __restrict__ bias,
    const float* __restrict__ stats_in, const float* __restrict__ g,
    const float* __restrict__ be, float* __restrict__ stats_out) {
  __shared__ float sred[2 * CC];
  const int t = threadIdx.x;
  const int l = t & 63;
  const int wv = t >> 6;
  const int m0 = blockIdx.x * 64 + wv * 16;
  const int row = m0 + (l & 15);
  const int kg = (l >> 4) * 8;
  sred[t] = 0.f;

  f32x4 acc[8];
#pragma unroll
  for (int i = 0; i < 8; ++i) acc[i] = (f32x4){0.f, 0.f, 0.f, 0.f};

#pragma unroll
  for (int ks = 0; ks < 4; ++ks) {
    bf16x8 ah;
    if (row < NN) {
      bf16x8 raw = *(const bf16x8*)&tmp16[row * CC + ks * 32 + kg];
#pragma unroll
      for (int i = 0; i < 8; ++i) {
        int c = ks * 32 + kg + i;
        float mu = stats_in[c] * (1.0f / NN);
        float var = fmaxf(stats_in[CC + c] * (1.0f / NN) - mu * mu, 0.f);
        float a = g[c] * rsqrtf(var + BN_EPS);
        float d = fmaf(-mu, a, be[c]);
        float v = bf2f((unsigned)(ushort_t)raw[i]);
        v = fmaxf(fmaf(v, a, d), 0.f);
        ah[i] = (short)f2bf(v);
      }
    } else {
#pragma unroll
      for (int i = 0; i < 8; ++i) ah[i] = 0;
    }
#pragma unroll
    for (int nt = 0; nt < 8; ++nt) {
      const int base = (ks * 8 + nt) * 512 + l * 8;
      bf16x8 wh = *(const bf16x8*)&Wp_hi[base];
      bf16x8 wl = *(const bf16x8*)&Wp_lo[base];
      acc[nt] = __builtin_amdgcn_mfma_f32_16x16x32_bf16(ah, wh, acc[nt], 0, 0, 0);
      acc[nt] = __builtin_amdgcn_mfma_f32_16x16x32_bf16(ah, wl, acc[nt], 0, 0, 0);
    }
  }

  __syncthreads();
  const int rbase = m0 + (l >> 4) * 4;
  const int cn = l & 15;
#pragma unroll
  for (int nt = 0; nt < 8; ++nt) {
    int c = nt * 16 + cn;
    float bv = bias[c];
    float s = 0.f, qq = 0.f;
#pragma unroll
    for (int r = 0; r < 4; ++r) {
      int rr = rbase + r;
      if (rr < NN) {
        float v = acc[nt][r] + bv;
        tmp16[rr * CC + c] = f2bf(v);
        s += v; qq += v * v;
      }
    }
    s += __shfl_xor(s, 16); s += __shfl_xor(s, 32);
    qq += __shfl_xor(qq, 16); qq += __shfl_xor(qq, 32);
    if ((l >> 4) == 0) {
      atomicAdd(&sred[c], s);
      atomicAdd(&sred[CC + c], qq);
    }
  }
  __syncthreads();
  atomicAdd(&stats_out[t], sred[t]);
}

// ---------------- apply: BN2(inline)+relu -> fp32 out slab + slice-major h16s ----------------
// grid (196, 8): blockIdx.y = slice; thread = one node's 16 channels of that slice.
__global__ __launch_bounds__(256) void apply_kernel(
    const ushort_t* __restrict__ t2, const float* __restrict__ stats2,
    const float* __restrict__ g2, const float* __restrict__ be2,
    float* __restrict__ outslab, ushort_t* __restrict__ h16s) {
  const int node = blockIdx.x * 256 + threadIdx.x;
  const int slice = blockIdx.y;
  if (node >= NN) return;
  const int c0 = slice * 16;

  const uint4* tp = (const uint4*)(t2 + node * CC + c0);
  uint4 r0 = tp[0], r1 = tp[1];
  unsigned w[4] = {r0.x, r0.y, r0.z, r0.w};
  unsigned w2[4] = {r1.x, r1.y, r1.z, r1.w};

  float vo[16];
#pragma unroll
  for (int j = 0; j < 8; ++j) {
    unsigned u = (j < 4) ? w[j] : w2[j - 4];
    vo[2 * j] = bf2f(u & 0xFFFFu);
    vo[2 * j + 1] = bf2f(u >> 16);
  }
#pragma unroll
  for (int j = 0; j < 16; ++j) {
    int c = c0 + j;
    float mu = stats2[c] * (1.0f / NN);
    float var = fmaxf(stats2[CC + c] * (1.0f / NN) - mu * mu, 0.f);
    float a = g2[c] * rsqrtf(var + BN_EPS);
    float d = fmaf(-mu, a, be2[c]);
    vo[j] = fmaxf(fmaf(vo[j], a, d), 0.f);
  }
  float* op = &outslab[node * CC + c0];
#pragma unroll
  for (int j = 0; j < 4; ++j) {
    float4 v = make_float4(vo[4 * j], vo[4 * j + 1], vo[4 * j + 2], vo[4 * j + 3]);
    *(float4*)&op[4 * j] = v;
  }
  if (h16s) {
    uint4 o0, o1;
    o0.x = (unsigned)f2bf(vo[0]) | ((unsigned)f2bf(vo[1]) << 16);
    o0.y = (unsigned)f2bf(vo[2]) | ((unsigned)f2bf(vo[3]) << 16);
    o0.z = (unsigned)f2bf(vo[4]) | ((unsigned)f2bf(vo[5]) << 16);
    o0.w = (unsigned)f2bf(vo[6]) | ((unsigned)f2bf(vo[7]) << 16);
    o1.x = (unsigned)f2bf(vo[8]) | ((unsigned)f2bf(vo[9]) << 16);
    o1.y = (unsigned)f2bf(vo[10]) | ((unsigned)f2bf(vo[11]) << 16);
    o1.z = (unsigned)f2bf(vo[12]) | ((unsigned)f2bf(vo[13]) << 16);
    o1.w = (unsigned)f2bf(vo[14]) | ((unsigned)f2bf(vo[15]) << 16);
    uint4* hp = (uint4*)(h16s + (slice * NN + node) * 16);
    hp[0] = o0;
    hp[1] = o1;
  }
}

// ---------------- launch ----------------
extern "C" void kernel_launch(void* const* d_in, const int* in_sizes, int n_in,
                              void* d_out, int out_size, void* d_ws, size_t ws_size,
                              hipStream_t stream) {
  const float* x    = (const float*)d_in[0];
  const int*   edge = (const int*)d_in[1];
  const float* fh_W = (const float*)d_in[3];
  const float* fh_b = (const float*)d_in[4];
  const float* W1   = (const float*)d_in[5];
  const float* b1   = (const float*)d_in[6];
  const float* g1   = (const float*)d_in[7];
  const float* be1  = (const float*)d_in[8];
  const float* W2   = (const float*)d_in[9];
  const float* b2   = (const float*)d_in[10];
  const float* g2   = (const float*)d_in[11];
  const float* be2  = (const float*)d_in[12];
  float* out = (float*)d_out;

  const int* src = edge;
  const int* dst = edge + NE;

  // workspace layout: [counts 50048][fill 50048][stats 1536f] zeroed together
  int* counts   = (int*)d_ws;
  int* fill     = counts + 50048;
  float* stats  = (float*)(fill + 50048);          // 6 x 256 floats
  int* starts   = (int*)(stats + 1536);            // 50048
  int* blocksum = starts + 50048;                  // 256
  int* bucket   = blocksum + 256;                  // 800000
  short* whi    = (short*)(bucket + NE);           // 7*16384
  short* wlo    = whi + 7 * CC * CC;               // 7*16384
  ushort_t* h16s = (ushort_t*)(wlo + 7 * CC * CC); // 8 x NN x 16 bf16 (12.8 MB, slice-major)
  ushort_t* aggs = h16s + SLAB;                    // 8 x NN x 16 bf16 (12.8 MB, slice-major)
  ushort_t* tmp16 = aggs + SLAB;                   // NN x CC bf16 (12.8 MB, ch-major)

  // CSR build + stats zero
  zero_int_kernel<<<(101632 + 255) / 256, 256, 0, stream>>>(counts, 101632);
  count_kernel<<<NE / 256, 256, 0, stream>>>(dst, counts);
  scan1_kernel<<<196, 256, 0, stream>>>(counts, starts, blocksum);
  scan2_kernel<<<1, 256, 0, stream>>>(blocksum, 196);
  scan3_kernel<<<196, 256, 0, stream>>>(starts, blocksum);
  fill_kernel<<<NE / 256, 256, 0, stream>>>(src, dst, starts, fill, bucket);

  // weight prep
  prep_w_kernel<<<7, 256, 0, stream>>>(fh_W, W1, W2, whi, wlo);

  // first head
  gemm0_kernel<<<782, 256, 0, stream>>>(x, whi, wlo, fh_b, out, h16s);

  for (int ly = 0; ly < 3; ++ly) {
    float* stats1 = stats + (ly * 2) * 256;
    float* stats2 = stats + (ly * 2 + 1) * 256;
    gather_kernel<<<25000, 256, 0, stream>>>(h16s, starts, counts, bucket, aggs);
    gemm1_kernel<<<782, 256, 0, stream>>>(
        aggs, whi + (1 + ly) * CC * CC, wlo + (1 + ly) * CC * CC, b1 + ly * CC, tmp16, stats1);
    gemm2_kernel<<<782, 256, 0, stream>>>(
        tmp16, whi + (4 + ly) * CC * CC, wlo + (4 + ly) * CC * CC, b2 + ly * CC,
        stats1, g1 + ly * CC, be1 + ly * CC, stats2);
    apply_kernel<<<dim3(196, 8), 256, 0, stream>>>(
        tmp16, stats2, g2 + ly * CC, be2 + ly * CC, out + (ly + 1) * SLAB,
        (ly < 2) ? h16s : (ushort_t*)nullptr);
  }
}